// Round 11
// baseline (407.385 us; speedup 1.0000x reference)
//
#include <hip/hip_runtime.h>
#include <hip/hip_fp16.h>
#include <math.h>

#define B_  4
#define CK_ 64
#define N_  4032   // memory axis (softmax axis), real
#define M_  4032   // query axis, real
#define NP_ 4096   // padded rows (4032..4095 zero-filled)
#define MP_ 4096

#define P1C 8   // pass1: 8 n-chunks x 8 tiles of 64 rows
#define P1T 8

typedef __attribute__((ext_vector_type(8))) short short8;   // 8 bf16 = 4 VGPRs (MFMA A/B frag)
typedef __attribute__((ext_vector_type(4))) float float4v;  // MFMA C/D frag
typedef __attribute__((ext_vector_type(4))) unsigned int uint4v;
typedef __attribute__((ext_vector_type(2))) unsigned int uint2v;

// fp32 -> bf16 bits, round-to-nearest-even (inputs are finite normals)
__device__ inline unsigned short f2bf(float x) {
    unsigned u = __float_as_uint(x);
    u += 0x7FFF + ((u >> 16) & 1);
    return (unsigned short)(u >> 16);
}
__device__ inline float bf2f(unsigned short h) {
    return __uint_as_float(((unsigned)h) << 16);
}
// u32 (2 packed fp16) -> float2, by value (vector lanes have no address)
__device__ inline float2 h2u_to_f2(unsigned v) {
    __half2 h;
    __builtin_memcpy(&h, &v, 4);
    return __half22float2(h);
}
// __half2 -> u32, by value
__device__ inline unsigned f2_to_h2u(float a, float b) {
    __half2 h = __floats2half2_rn(a, b);
    unsigned u;
    __builtin_memcpy(&u, &h, 4);
    return u;
}

// ---------------- Prep: transpose to [n][64] bf16 hi/lo + eu_n / ev_m -------
// in [B][64][N] fp32 -> dst_hi/dst_lo [B][NP][64] bf16 (rows >= N_ zeroed);
// eu[b][n] = 0.125*||mk_n||^2, ev[b][m] = 0.125*||qk_m||^2; 1e30 on pad rows
// (so w = exp(0.25*dot - eu - ev) is exactly 0 there).
__global__ __launch_bounds__(256) void prep_kernel(
    const float* __restrict__ mk, const float* __restrict__ qk,
    unsigned short* __restrict__ mk_hi, unsigned short* __restrict__ mk_lo,
    unsigned short* __restrict__ qk_hi, unsigned short* __restrict__ qk_lo,
    float* __restrict__ eu, float* __restrict__ ev)
{
    __shared__ float tile[64][65];
    __shared__ float sred[4][64];
    const int t  = threadIdx.x;
    const int n0 = blockIdx.x * 64;
    const int b  = blockIdx.y;
    const int which = blockIdx.z;
    const bool pad = (n0 >= N_);            // block-uniform

    const float* src = (which == 0 ? mk : qk) + (size_t)b * CK_ * N_;
    unsigned short* dhi = (which == 0 ? mk_hi : qk_hi) + (size_t)b * NP_ * CK_;
    unsigned short* dlo = (which == 0 ? mk_lo : qk_lo) + (size_t)b * NP_ * CK_;

    if (!pad) {
        #pragma unroll
        for (int i = 0; i < 16; ++i) {
            const int idx = t + 256 * i;
            const int c = idx >> 6, n = idx & 63;
            tile[c][n] = src[(size_t)c * N_ + n0 + n];
        }
    } else {
        #pragma unroll
        for (int i = 0; i < 16; ++i) {
            const int idx = t + 256 * i;
            tile[idx >> 6][idx & 63] = 0.f;
        }
    }
    __syncthreads();

    const int n = t & 63;
    const int g = t >> 6;          // c-group of 16
    unsigned short hbits[16], lbits[16];
    float ssq = 0.f;
    #pragma unroll
    for (int i = 0; i < 16; ++i) {
        const float x = tile[g * 16 + i][n];
        const unsigned short h = f2bf(x);
        hbits[i] = h;
        lbits[i] = f2bf(x - bf2f(h));
        ssq = fmaf(x, x, ssq);
    }
    {
        union { short8 vv; unsigned short s[8]; } p0, p1, q0, q1;
        #pragma unroll
        for (int i = 0; i < 8; ++i) {
            p0.s[i] = hbits[i]; p1.s[i] = hbits[8 + i];
            q0.s[i] = lbits[i]; q1.s[i] = lbits[8 + i];
        }
        const size_t base = (size_t)(n0 + n) * CK_ + g * 16;
        *(short8*)(dhi + base)     = p0.vv;
        *(short8*)(dhi + base + 8) = p1.vv;
        *(short8*)(dlo + base)     = q0.vv;
        *(short8*)(dlo + base + 8) = q1.vv;
    }
    sred[g][n] = ssq;
    __syncthreads();
    if (t < 64) {
        const float tot = sred[0][t] + sred[1][t] + sred[2][t] + sred[3][t];
        float* dst = (which == 0 ? eu : ev);
        dst[(size_t)b * NP_ + n0 + t] = pad ? 1e30f : 0.125f * tot;
    }
}

// MFMA 16x16x32 bf16 layouts (verified m89/m91):
//   A: A[m = lane&15][k = (lane>>4)*8 + j]  -> 16B contiguous per lane
//   B: B[k = (lane>>4)*8 + j][n = lane&15]
//   C/D: D[row][col], col = lane&15, row = (lane>>4)*4 + reg

// ---------------- Pass 1: the ONLY GEMM ------------------------------------
// Grid (MP/128, P1C, B). Block 512 = 8 waves (wm 0..3 m-strips of 32,
// wn 0..1 n-halves). A = qk (m rows), B = mk (n cols) -> D row=m, col=n.
// w[n][m] = exp(0.25*dot - eu_n - ev_m) = exp(-||mk-qk||^2/8) <= 1 (fp16-safe).
// w tiles staged in LDS (double-buffered) then written COALESCED (256 B/row)
// as fp16 into the first half of out row n (out doubles as scratch).
// Also accumulates fp32 colsums -> psum[b][chunk][m].
__global__ __launch_bounds__(512) void pass1_kernel(
    const unsigned short* __restrict__ mk_hi, const unsigned short* __restrict__ mk_lo,
    const unsigned short* __restrict__ qk_hi, const unsigned short* __restrict__ qk_lo,
    const float* __restrict__ eu, const float* __restrict__ ev,
    float* __restrict__ psum, float* __restrict__ out)
{
    __shared__ unsigned short wt[2][64][136];   // 64 n-rows x 128 m (pitch 136)
    __shared__ float cs[2][128];
    const int t = threadIdx.x;
    const int wave = t >> 6, lane = t & 63;
    const int wn = wave & 1, wm = wave >> 1;
    const int lcol = lane & 15;
    const int quad = lane >> 4;
    const int chunk = blockIdx.y;
    const int b = blockIdx.z;
    const int m_blk  = blockIdx.x * 128;
    const int m_base = m_blk + wm * 32;

    const unsigned short* mh = mk_hi + (size_t)b * NP_ * CK_;
    const unsigned short* ml = mk_lo + (size_t)b * NP_ * CK_;
    const unsigned short* qh = qk_hi + (size_t)b * NP_ * CK_;
    const unsigned short* ql = qk_lo + (size_t)b * NP_ * CK_;
    const float* eub = eu + (size_t)b * NP_;

    // hoist A (qk) fragments: mg = 16-row group (m), kc = k-chunk of 32
    short8 qah[2][2], qal[2][2];
    #pragma unroll
    for (int mg = 0; mg < 2; ++mg) {
        const size_t mrow = (size_t)(m_base + mg * 16 + lcol) * CK_;
        #pragma unroll
        for (int kc = 0; kc < 2; ++kc) {
            const size_t off = mrow + kc * 32 + quad * 8;
            qah[mg][kc] = *(const short8*)(qh + off);
            qal[mg][kc] = *(const short8*)(ql + off);
        }
    }

    // ev per lane: m = m_base + mg*16 + quad*4 + r (4 consecutive)
    float4v ev4[2];
    #pragma unroll
    for (int mg = 0; mg < 2; ++mg)
        ev4[mg] = *(const float4v*)(ev + (size_t)b * NP_ + m_base + mg * 16 + quad * 4);

    unsigned short* wb = (unsigned short*)(out + (size_t)b * N_ * M_);

    float ps[2][4];
    #pragma unroll
    for (int mg = 0; mg < 2; ++mg)
        #pragma unroll
        for (int r = 0; r < 4; ++r) ps[mg][r] = 0.f;

    const int crow = t >> 3;     // coop-writer row (0..63)
    const int cseg = t & 7;      // coop-writer 16-m segment (0..7)
    const bool mseg_ok = (m_blk + cseg * 16) < N_;   // 4032 % 16 == 0

    int p = 0;
    for (int it = chunk * P1T; it < chunk * P1T + P1T; ++it) {
        const int n_base = it * 64 + wn * 32;

        short8 bh[2][2], bl[2][2];
        #pragma unroll
        for (int ng = 0; ng < 2; ++ng) {
            const size_t nrow = (size_t)(n_base + ng * 16 + lcol) * CK_;
            #pragma unroll
            for (int kc = 0; kc < 2; ++kc) {
                const size_t off = nrow + kc * 32 + quad * 8;
                bh[ng][kc] = *(const short8*)(mh + off);
                bl[ng][kc] = *(const short8*)(ml + off);
            }
        }
        float eun[2];
        #pragma unroll
        for (int ng = 0; ng < 2; ++ng)
            eun[ng] = eub[n_base + ng * 16 + lcol];

        #pragma unroll
        for (int mg = 0; mg < 2; ++mg) {
            #pragma unroll
            for (int ng = 0; ng < 2; ++ng) {
                float4v a1 = {0.f, 0.f, 0.f, 0.f};
                float4v a2 = {0.f, 0.f, 0.f, 0.f};
                __builtin_amdgcn_s_setprio(1);
                #pragma unroll
                for (int kc = 0; kc < 2; ++kc) {
                    a1 = __builtin_amdgcn_mfma_f32_16x16x32_bf16(qah[mg][kc], bh[ng][kc], a1, 0, 0, 0);
                    a2 = __builtin_amdgcn_mfma_f32_16x16x32_bf16(qah[mg][kc], bl[ng][kc], a2, 0, 0, 0);
                    a2 = __builtin_amdgcn_mfma_f32_16x16x32_bf16(qal[mg][kc], bh[ng][kc], a2, 0, 0, 0);
                }
                __builtin_amdgcn_s_setprio(0);
                float4v wv;
                #pragma unroll
                for (int r = 0; r < 4; ++r) {
                    const float dot = a1[r] + a2[r];
                    const float x = fmaf(dot, 0.25f, -eun[ng] - ev4[mg][r]);
                    wv[r] = __expf(x);
                    ps[mg][r] += wv[r];
                }
                const unsigned ua = f2_to_h2u(wv[0], wv[1]);
                const unsigned ub = f2_to_h2u(wv[2], wv[3]);
                uint2v pk;
                pk.x = ua;   // element ASSIGNMENT is legal on ext vectors
                pk.y = ub;   // (element address-of is not)
                const int n_rel = wn * 32 + ng * 16 + lcol;
                const int m_rel = wm * 32 + mg * 16 + quad * 4;
                *(uint2v*)&wt[p][n_rel][m_rel] = pk;
            }
        }
        __syncthreads();

        // cooperative coalesced write: 64 rows x 256 B (full cache lines)
        const int n_g = it * 64 + crow;
        if (n_g < N_ && mseg_ok) {
            const uint4v* s = (const uint4v*)&wt[p][crow][cseg * 16];
            uint4v v0 = s[0], v1 = s[1];
            unsigned short* dst = wb + (size_t)n_g * (2 * M_) + m_blk + cseg * 16;
            __builtin_nontemporal_store(v0, (uint4v*)dst);
            __builtin_nontemporal_store(v1, (uint4v*)(dst + 8));
        }
        p ^= 1;   // next iter writes the other LDS buffer (no 2nd barrier)
    }

    // reduce over the 16 n-lanes (lcol) -> per-(m) partial colsum
    #pragma unroll
    for (int mg = 0; mg < 2; ++mg)
        #pragma unroll
        for (int r = 0; r < 4; ++r) {
            float s = ps[mg][r];
            s += __shfl_xor(s, 1);
            s += __shfl_xor(s, 2);
            s += __shfl_xor(s, 4);
            s += __shfl_xor(s, 8);
            ps[mg][r] = s;
        }
    if (lcol == 0) {
        #pragma unroll
        for (int mg = 0; mg < 2; ++mg)
            #pragma unroll
            for (int r = 0; r < 4; ++r)
                cs[wn][wm * 32 + mg * 16 + quad * 4 + r] = ps[mg][r];
    }
    __syncthreads();
    if (t < 128) {
        psum[((size_t)b * P1C + chunk) * MP_ + blockIdx.x * 128 + t] =
            cs[0][t] + cs[1][t];
    }
}

// ---------------- Reduce: psum partials -> rinv -----------------------------
__global__ __launch_bounds__(256) void reduce_kernel(
    const float* __restrict__ psum, float* __restrict__ rinv)
{
    const int m = blockIdx.x * 256 + threadIdx.x;
    const int b = blockIdx.y;
    float s = 0.f;
    #pragma unroll
    for (int c = 0; c < P1C; ++c)
        s += psum[((size_t)b * P1C + c) * MP_ + m];
    rinv[(size_t)b * MP_ + m] = 1.f / s;   // pad m: inf, never read
}

// ---------------- Pass 2: streaming scale (no GEMM) -------------------------
// One block per (n, b) out row. Reads fp16 w from the first 8064 B of the
// row, scales by rinv[m], writes the full fp32 row. In-place safe: the block
// reads ONLY its own row's w, barrier (with vmcnt pin), then overwrites.
__global__ __launch_bounds__(256) void pass2_kernel(
    const float* __restrict__ rinv, float* __restrict__ out)
{
    const int t = threadIdx.x;
    const int n = blockIdx.x;
    const int b = blockIdx.y;
    float* row = out + ((size_t)b * N_ + n) * M_;
    const unsigned short* wr = (const unsigned short*)row;
    const float* rv = rinv + (size_t)b * MP_;

    const int c0 = t;            // chunk = 8 m's; 504 chunks per row
    const int c1 = t + 256;
    const bool has1 = (c1 < (M_ / 8));

    uint4v q0 = *(const uint4v*)(wr + c0 * 8);
    float4v ra0 = *(const float4v*)(rv + c0 * 8);
    float4v rb0 = *(const float4v*)(rv + c0 * 8 + 4);
    uint4v q1;
    float4v ra1, rb1;
    if (has1) {
        q1  = *(const uint4v*)(wr + c1 * 8);
        ra1 = *(const float4v*)(rv + c1 * 8);
        rb1 = *(const float4v*)(rv + c1 * 8 + 4);
    }

    // convert+scale BEFORE the barrier (forces load completion into regs)
    float4v xa0, xb0, xa1, xb1;
    {
        float2 f0 = h2u_to_f2(q0.x);
        float2 f1 = h2u_to_f2(q0.y);
        float2 f2 = h2u_to_f2(q0.z);
        float2 f3 = h2u_to_f2(q0.w);
        xa0 = (float4v){f0.x * ra0[0], f0.y * ra0[1], f1.x * ra0[2], f1.y * ra0[3]};
        xb0 = (float4v){f2.x * rb0[0], f2.y * rb0[1], f3.x * rb0[2], f3.y * rb0[3]};
    }
    if (has1) {
        float2 f0 = h2u_to_f2(q1.x);
        float2 f1 = h2u_to_f2(q1.y);
        float2 f2 = h2u_to_f2(q1.z);
        float2 f3 = h2u_to_f2(q1.w);
        xa1 = (float4v){f0.x * ra1[0], f0.y * ra1[1], f1.x * ra1[2], f1.y * ra1[3]};
        xb1 = (float4v){f2.x * rb1[0], f2.y * rb1[1], f3.x * rb1[2], f3.y * rb1[3]};
    }

    // pin: all w-reads complete before any lane crosses the barrier
    asm volatile("s_waitcnt vmcnt(0)" ::: "memory");
    __syncthreads();

    __builtin_nontemporal_store(xa0, (float4v*)(row + c0 * 8));
    __builtin_nontemporal_store(xb0, (float4v*)(row + c0 * 8 + 4));
    if (has1) {
        __builtin_nontemporal_store(xa1, (float4v*)(row + c1 * 8));
        __builtin_nontemporal_store(xb1, (float4v*)(row + c1 * 8 + 4));
    }
}

extern "C" void kernel_launch(void* const* d_in, const int* in_sizes, int n_in,
                              void* d_out, int out_size, void* d_ws, size_t ws_size,
                              hipStream_t stream) {
    const float* mk = (const float*)d_in[0];
    const float* qk = (const float*)d_in[1];
    float* out = (float*)d_out;

    // ws: mk_hi | mk_lo | qk_hi | qk_lo (bf16 [B][NP][64]) | eu | ev | psum | rinv
    unsigned short* mk_hi = (unsigned short*)d_ws;
    unsigned short* mk_lo = mk_hi + (size_t)B_ * NP_ * CK_;
    unsigned short* qk_hi = mk_lo + (size_t)B_ * NP_ * CK_;
    unsigned short* qk_lo = qk_hi + (size_t)B_ * NP_ * CK_;
    float* eu   = (float*)(qk_lo + (size_t)B_ * NP_ * CK_);
    float* ev   = eu + (size_t)B_ * NP_;
    float* psum = ev + (size_t)B_ * NP_;           // [B][P1C][MP]
    float* rinv = psum + (size_t)B_ * P1C * MP_;   // [B][MP]

    prep_kernel<<<dim3(NP_ / 64, B_, 2), 256, 0, stream>>>(mk, qk, mk_hi, mk_lo, qk_hi, qk_lo, eu, ev);
    pass1_kernel<<<dim3(MP_ / 128, P1C, B_), 512, 0, stream>>>(mk_hi, mk_lo, qk_hi, qk_lo, eu, ev, psum, out);
    reduce_kernel<<<dim3(MP_ / 256, B_), 256, 0, stream>>>(psum, rinv);
    pass2_kernel<<<dim3(N_, B_), 256, 0, stream>>>(rinv, out);
}

// Round 12
// 381.796 us; speedup vs baseline: 1.0670x; 1.0670x over previous
//
#include <hip/hip_runtime.h>
#include <hip/hip_fp16.h>
#include <math.h>

#define B_  4
#define CK_ 64
#define N_  4032   // memory axis (softmax axis), real
#define M_  4032   // query axis, real
#define NP_ 4096   // padded rows (4032..4095 zero-filled)
#define MP_ 4096

#define P1C 8   // pass1: 8 n-chunks x 8 tiles of 64 rows
#define P1T 8

typedef __attribute__((ext_vector_type(8))) short short8;   // 8 bf16 = 4 VGPRs (MFMA A/B frag)
typedef __attribute__((ext_vector_type(4))) float float4v;  // MFMA C/D frag

// fp32 -> bf16 bits, round-to-nearest-even (inputs are finite normals)
__device__ inline unsigned short f2bf(float x) {
    unsigned u = __float_as_uint(x);
    u += 0x7FFF + ((u >> 16) & 1);
    return (unsigned short)(u >> 16);
}
__device__ inline float bf2f(unsigned short h) {
    return __uint_as_float(((unsigned)h) << 16);
}

// ---------------- Prep: transpose to [n][64] bf16 hi/lo + u_n / v_m --------
// in [B][64][N] fp32 -> dst_hi/dst_lo [B][NP][64] bf16 (rows >= N_ zeroed);
// u[b][n] = exp(-0.125*||mk_n||^2), v[b][m] = exp(-0.125*||qk_m||^2); 0 on pad.
__global__ __launch_bounds__(256) void prep_kernel(
    const float* __restrict__ mk, const float* __restrict__ qk,
    unsigned short* __restrict__ mk_hi, unsigned short* __restrict__ mk_lo,
    unsigned short* __restrict__ qk_hi, unsigned short* __restrict__ qk_lo,
    float* __restrict__ u, float* __restrict__ v)
{
    __shared__ float tile[64][65];
    __shared__ float sred[4][64];
    const int t  = threadIdx.x;
    const int n0 = blockIdx.x * 64;
    const int b  = blockIdx.y;
    const int which = blockIdx.z;
    const bool pad = (n0 >= N_);            // block-uniform

    const float* src = (which == 0 ? mk : qk) + (size_t)b * CK_ * N_;
    unsigned short* dhi = (which == 0 ? mk_hi : qk_hi) + (size_t)b * NP_ * CK_;
    unsigned short* dlo = (which == 0 ? mk_lo : qk_lo) + (size_t)b * NP_ * CK_;

    if (!pad) {
        #pragma unroll
        for (int i = 0; i < 16; ++i) {
            const int idx = t + 256 * i;
            const int c = idx >> 6, n = idx & 63;
            tile[c][n] = src[(size_t)c * N_ + n0 + n];
        }
    } else {
        #pragma unroll
        for (int i = 0; i < 16; ++i) {
            const int idx = t + 256 * i;
            tile[idx >> 6][idx & 63] = 0.f;
        }
    }
    __syncthreads();

    const int n = t & 63;
    const int g = t >> 6;          // c-group of 16
    unsigned short hbits[16], lbits[16];
    float ssq = 0.f;
    #pragma unroll
    for (int i = 0; i < 16; ++i) {
        const float x = tile[g * 16 + i][n];
        const unsigned short h = f2bf(x);
        hbits[i] = h;
        lbits[i] = f2bf(x - bf2f(h));
        ssq = fmaf(x, x, ssq);
    }
    {
        union { short8 vv; unsigned short s[8]; } p0, p1, q0, q1;
        #pragma unroll
        for (int i = 0; i < 8; ++i) {
            p0.s[i] = hbits[i]; p1.s[i] = hbits[8 + i];
            q0.s[i] = lbits[i]; q1.s[i] = lbits[8 + i];
        }
        const size_t base = (size_t)(n0 + n) * CK_ + g * 16;
        *(short8*)(dhi + base)     = p0.vv;
        *(short8*)(dhi + base + 8) = p1.vv;
        *(short8*)(dlo + base)     = q0.vv;
        *(short8*)(dlo + base + 8) = q1.vv;
    }
    sred[g][n] = ssq;
    __syncthreads();
    if (t < 64) {
        const float tot = sred[0][t] + sred[1][t] + sred[2][t] + sred[3][t];
        float* dst = (which == 0 ? u : v);
        dst[(size_t)b * NP_ + n0 + t] = pad ? 0.f : __expf(-0.125f * tot);
    }
}

// MFMA 16x16x32 bf16 layouts (verified m89/m91):
//   A: A[m = lane&15][k = (lane>>4)*8 + j]  -> 16B contiguous per lane
//   B: B[k = (lane>>4)*8 + j][n = lane&15]
//   C/D: D[row][col], col = lane&15, row = (lane>>4)*4 + reg

// ---------------- Pass 1: the ONLY GEMM (2-deep software pipeline) ----------
// Grid (MP/128, P1C, B). Block 512 = 8 waves (wm 0..3 m-strips of 32,
// wn 0..1 n-halves). A = qk (m rows), B = mk (n cols) -> D row=m, col=n.
// w[n][m] = u_n * exp(0.25*dot) * v_m = exp(-||mk-qk||^2/8) <= 1 (fp16-safe).
// w stored fp16 scattered into the first half of out row n (L2 merges the
// lines; R11 showed LDS-staged coalescing is a net loss). Pipeline: prefetch
// tile j+1's B-fragments into the alternate register buffer before tile j's
// MFMA/exp/store work (static buffer indices -- no dynamic indexing).
__global__ __launch_bounds__(512) void pass1_kernel(
    const unsigned short* __restrict__ mk_hi, const unsigned short* __restrict__ mk_lo,
    const unsigned short* __restrict__ qk_hi, const unsigned short* __restrict__ qk_lo,
    const float* __restrict__ u, const float* __restrict__ v,
    float* __restrict__ psum, float* __restrict__ out)
{
    __shared__ float cs[2][128];
    const int t = threadIdx.x;
    const int wave = t >> 6, lane = t & 63;
    const int wn = wave & 1, wm = wave >> 1;
    const int lcol = lane & 15;
    const int quad = lane >> 4;
    const int chunk = blockIdx.y;
    const int b = blockIdx.z;
    const int m_base = blockIdx.x * 128 + wm * 32;

    const unsigned short* mh = mk_hi + (size_t)b * NP_ * CK_;
    const unsigned short* ml = mk_lo + (size_t)b * NP_ * CK_;
    const unsigned short* qh = qk_hi + (size_t)b * NP_ * CK_;
    const unsigned short* ql = qk_lo + (size_t)b * NP_ * CK_;
    const float* ub = u + (size_t)b * NP_;

    // hoist A (qk) fragments: mg = 16-row group (m), kc = k-chunk of 32
    short8 qah[2][2], qal[2][2];
    #pragma unroll
    for (int mg = 0; mg < 2; ++mg) {
        const size_t mrow = (size_t)(m_base + mg * 16 + lcol) * CK_;
        #pragma unroll
        for (int kc = 0; kc < 2; ++kc) {
            const size_t off = mrow + kc * 32 + quad * 8;
            qah[mg][kc] = *(const short8*)(qh + off);
            qal[mg][kc] = *(const short8*)(ql + off);
        }
    }

    // v per lane: m = m_base + mg*16 + quad*4 + r (4 consecutive)
    float4v vv[2];
    #pragma unroll
    for (int mg = 0; mg < 2; ++mg)
        vv[mg] = *(const float4v*)(v + (size_t)b * NP_ + m_base + mg * 16 + quad * 4);

    const bool mv0 = (m_base < N_);
    const bool mv1 = (m_base + 16 < N_);

    unsigned short* wb = (unsigned short*)(out + (size_t)b * N_ * M_);

    float ps[2][4];
    #pragma unroll
    for (int mg = 0; mg < 2; ++mg)
        #pragma unroll
        for (int r = 0; r < 4; ++r) ps[mg][r] = 0.f;

    // ---- pipeline helpers (register double-buffer, static indices) ----
    auto LOADB = [&](int it, short8 (&BH)[2][2], short8 (&BL)[2][2], float (&UN)[2]) {
        const int nb = it * 64 + wn * 32;
        #pragma unroll
        for (int ng = 0; ng < 2; ++ng) {
            const size_t nrow = (size_t)(nb + ng * 16 + lcol) * CK_;
            #pragma unroll
            for (int kc = 0; kc < 2; ++kc) {
                const size_t off = nrow + kc * 32 + quad * 8;
                BH[ng][kc] = *(const short8*)(mh + off);
                BL[ng][kc] = *(const short8*)(ml + off);
            }
            UN[ng] = ub[nb + ng * 16 + lcol];
        }
    };

    auto COMPUTE = [&](const short8 (&BH)[2][2], const short8 (&BL)[2][2],
                       const float (&UN)[2], int n_base) {
        const bool nv0 = (n_base < N_);        // tiles 32-aligned; 4032 % 32 == 0
        const bool nv1 = (n_base + 16 < N_);
        #pragma unroll
        for (int mg = 0; mg < 2; ++mg) {
            #pragma unroll
            for (int ng = 0; ng < 2; ++ng) {
                float4v a1 = {0.f, 0.f, 0.f, 0.f};
                float4v a2 = {0.f, 0.f, 0.f, 0.f};
                __builtin_amdgcn_s_setprio(1);
                #pragma unroll
                for (int kc = 0; kc < 2; ++kc) {
                    a1 = __builtin_amdgcn_mfma_f32_16x16x32_bf16(qah[mg][kc], BH[ng][kc], a1, 0, 0, 0);
                    a2 = __builtin_amdgcn_mfma_f32_16x16x32_bf16(qah[mg][kc], BL[ng][kc], a2, 0, 0, 0);
                    a2 = __builtin_amdgcn_mfma_f32_16x16x32_bf16(qal[mg][kc], BH[ng][kc], a2, 0, 0, 0);
                }
                __builtin_amdgcn_s_setprio(0);
                float4v wv;
                #pragma unroll
                for (int r = 0; r < 4; ++r) {
                    const float dot = a1[r] + a2[r];
                    wv[r] = UN[ng] * __expf(0.25f * dot) * vv[mg][r];
                    ps[mg][r] += wv[r];
                }
                if ((ng == 0 ? nv0 : nv1) && (mg == 0 ? mv0 : mv1)) {
                    __half2 hA = __floats2half2_rn(wv[0], wv[1]);
                    __half2 hB = __floats2half2_rn(wv[2], wv[3]);
                    uint2 pk;
                    pk.x = *(unsigned*)&hA;
                    pk.y = *(unsigned*)&hB;
                    *(uint2*)(wb + (size_t)(n_base + ng * 16 + lcol) * (2 * M_)
                                  + m_base + mg * 16 + quad * 4) = pk;
                }
            }
        }
    };

    short8 bhA[2][2], blA[2][2], bhB[2][2], blB[2][2];
    float unA[2], unB[2];
    const int it0 = chunk * P1T;

    LOADB(it0, bhA, blA, unA);
    #pragma unroll
    for (int j = 0; j < P1T; j += 2) {
        if (j + 1 < P1T) LOADB(it0 + j + 1, bhB, blB, unB);   // prefetch odd tile
        COMPUTE(bhA, blA, unA, (it0 + j) * 64 + wn * 32);
        if (j + 2 < P1T) LOADB(it0 + j + 2, bhA, blA, unA);   // prefetch next even
        if (j + 1 < P1T) COMPUTE(bhB, blB, unB, (it0 + j + 1) * 64 + wn * 32);
    }

    // reduce over the 16 n-lanes (lcol) -> per-(m) partial colsum
    #pragma unroll
    for (int mg = 0; mg < 2; ++mg)
        #pragma unroll
        for (int r = 0; r < 4; ++r) {
            float s = ps[mg][r];
            s += __shfl_xor(s, 1);
            s += __shfl_xor(s, 2);
            s += __shfl_xor(s, 4);
            s += __shfl_xor(s, 8);
            ps[mg][r] = s;
        }
    if (lcol == 0) {
        #pragma unroll
        for (int mg = 0; mg < 2; ++mg)
            #pragma unroll
            for (int r = 0; r < 4; ++r)
                cs[wn][wm * 32 + mg * 16 + quad * 4 + r] = ps[mg][r];
    }
    __syncthreads();
    if (t < 128) {
        psum[((size_t)b * P1C + chunk) * MP_ + blockIdx.x * 128 + t] =
            cs[0][t] + cs[1][t];
    }
}

// ---------------- Reduce: psum partials -> rinv -----------------------------
__global__ __launch_bounds__(256) void reduce_kernel(
    const float* __restrict__ psum, float* __restrict__ rinv)
{
    const int m = blockIdx.x * 256 + threadIdx.x;
    const int b = blockIdx.y;
    float s = 0.f;
    #pragma unroll
    for (int c = 0; c < P1C; ++c)
        s += psum[((size_t)b * P1C + c) * MP_ + m];
    rinv[(size_t)b * MP_ + m] = 1.f / s;   // pad m: inf, never read
}

// ---------------- Pass 2: streaming scale (no GEMM) -------------------------
// One block per (n, b) out row. Reads fp16 w from the first 8064 B of the
// row, scales by rinv[m], writes the full fp32 row. In-place safe: the block
// reads ONLY its own row's w, barrier (with vmcnt pin), then overwrites.
__global__ __launch_bounds__(256) void pass2_kernel(
    const float* __restrict__ rinv, float* __restrict__ out)
{
    const int t = threadIdx.x;
    const int n = blockIdx.x;
    const int b = blockIdx.y;
    float* row = out + ((size_t)b * N_ + n) * M_;
    const unsigned short* wr = (const unsigned short*)row;
    const float* rv = rinv + (size_t)b * MP_;

    const int c0 = t;            // chunk = 8 m's; 504 chunks per row
    const int c1 = t + 256;
    const bool has1 = (c1 < (M_ / 8));

    uint4 q0 = *(const uint4*)(wr + c0 * 8);
    float4v ra0 = *(const float4v*)(rv + c0 * 8);
    float4v rb0 = *(const float4v*)(rv + c0 * 8 + 4);
    uint4 q1;
    float4v ra1, rb1;
    if (has1) {
        q1  = *(const uint4*)(wr + c1 * 8);
        ra1 = *(const float4v*)(rv + c1 * 8);
        rb1 = *(const float4v*)(rv + c1 * 8 + 4);
    }

    // convert+scale BEFORE the barrier (forces load completion into regs)
    float4v xa0, xb0, xa1, xb1;
    {
        float2 f0 = __half22float2(*(const __half2*)&q0.x);
        float2 f1 = __half22float2(*(const __half2*)&q0.y);
        float2 f2 = __half22float2(*(const __half2*)&q0.z);
        float2 f3 = __half22float2(*(const __half2*)&q0.w);
        xa0 = (float4v){f0.x * ra0[0], f0.y * ra0[1], f1.x * ra0[2], f1.y * ra0[3]};
        xb0 = (float4v){f2.x * rb0[0], f2.y * rb0[1], f3.x * rb0[2], f3.y * rb0[3]};
    }
    if (has1) {
        float2 f0 = __half22float2(*(const __half2*)&q1.x);
        float2 f1 = __half22float2(*(const __half2*)&q1.y);
        float2 f2 = __half22float2(*(const __half2*)&q1.z);
        float2 f3 = __half22float2(*(const __half2*)&q1.w);
        xa1 = (float4v){f0.x * ra1[0], f0.y * ra1[1], f1.x * ra1[2], f1.y * ra1[3]};
        xb1 = (float4v){f2.x * rb1[0], f2.y * rb1[1], f3.x * rb1[2], f3.y * rb1[3]};
    }

    // pin: all w-reads complete before any lane crosses the barrier
    asm volatile("s_waitcnt vmcnt(0)" ::: "memory");
    __syncthreads();

    __builtin_nontemporal_store(xa0, (float4v*)(row + c0 * 8));
    __builtin_nontemporal_store(xb0, (float4v*)(row + c0 * 8 + 4));
    if (has1) {
        __builtin_nontemporal_store(xa1, (float4v*)(row + c1 * 8));
        __builtin_nontemporal_store(xb1, (float4v*)(row + c1 * 8 + 4));
    }
}

extern "C" void kernel_launch(void* const* d_in, const int* in_sizes, int n_in,
                              void* d_out, int out_size, void* d_ws, size_t ws_size,
                              hipStream_t stream) {
    const float* mk = (const float*)d_in[0];
    const float* qk = (const float*)d_in[1];
    float* out = (float*)d_out;

    // ws: mk_hi | mk_lo | qk_hi | qk_lo (bf16 [B][NP][64]) | u | v | psum | rinv
    unsigned short* mk_hi = (unsigned short*)d_ws;
    unsigned short* mk_lo = mk_hi + (size_t)B_ * NP_ * CK_;
    unsigned short* qk_hi = mk_lo + (size_t)B_ * NP_ * CK_;
    unsigned short* qk_lo = qk_hi + (size_t)B_ * NP_ * CK_;
    float* u    = (float*)(qk_lo + (size_t)B_ * NP_ * CK_);
    float* v    = u + (size_t)B_ * NP_;
    float* psum = v + (size_t)B_ * NP_;            // [B][P1C][MP]
    float* rinv = psum + (size_t)B_ * P1C * MP_;   // [B][MP]

    prep_kernel<<<dim3(NP_ / 64, B_, 2), 256, 0, stream>>>(mk, qk, mk_hi, mk_lo, qk_hi, qk_lo, u, v);
    pass1_kernel<<<dim3(MP_ / 128, P1C, B_), 512, 0, stream>>>(mk_hi, mk_lo, qk_hi, qk_lo, u, v, psum, out);
    reduce_kernel<<<dim3(MP_ / 256, B_), 256, 0, stream>>>(psum, rinv);
    pass2_kernel<<<dim3(N_, B_), 256, 0, stream>>>(rinv, out);
}